// Round 1
// 125.821 us; speedup vs baseline: 1.1552x; 1.1552x over previous
//
#include <hip/hip_runtime.h>
#include <hip/hip_bf16.h>
#include <stdint.h>

#define KD 512
#define OD 8
#define SZ (KD*KD*OD)       // 2097152 elements per tensor (A,B,C)
#define PLANE (KD*KD)       // 262144

typedef short v8s __attribute__((ext_vector_type(8)));
typedef float v4f __attribute__((ext_vector_type(4)));

#define GLOBAL_AS __attribute__((address_space(1)))
#define LDS_AS __attribute__((address_space(3)))

static __device__ __forceinline__ unsigned short f2bf(float f) {
    union { float f; unsigned int u; } v; v.f = f;
    unsigned int u = v.u;
    unsigned int r = u + 0x7FFF + ((u >> 16) & 1);   // RNE
    return (unsigned short)(r >> 16);
}

static __device__ __forceinline__ void async16(const unsigned short* g, unsigned short* l) {
    __builtin_amdgcn_global_load_lds((const GLOBAL_AS void*)g, (LDS_AS void*)l, 16, 0, 0);
}

// ---------------------------------------------------------------------------
// Pack: W[x][j][k] = A[j,k,x]*Pb[j]*Pc[k]   (bf16, k-contiguous)
//       X[y][i][k] = B[k,i,y]*Pa[i]         (bf16, k-contiguous, via LDS transpose)
// blocks [0,512): A-pack (one j per block). blocks [512,768): B-pack 32x32 tiles.
// block 0 also zeroes the probs accumulator (ws is poisoned 0xAA each call).
// ---------------------------------------------------------------------------
__global__ __launch_bounds__(256) void pack_kernel(const float* __restrict__ yp,
                                                   unsigned short* __restrict__ Wbf,
                                                   unsigned short* __restrict__ Xbf,
                                                   float* __restrict__ probs_acc) {
    __shared__ unsigned short lds[8 * 32 * 40];   // [y][di][dk], dk padded 32->40
    const float* Pa = yp;
    const float* Pb = yp + KD;
    const float* Pc = yp + 2 * KD;
    const float* A  = yp + 3 * KD;
    const float* B  = A + SZ;
    const int b = blockIdx.x;
    const int t = threadIdx.x;

    if (b == 0) { probs_acc[t] = 0.0f; probs_acc[t + 256] = 0.0f; }

    if (b < 512) {
        // ---- A-pack: j = b, each thread handles k0 = 2t, 2t+1 ----
        const int j = b;
        const float pb = Pb[j];
        const int k0 = 2 * t;
        const float4* src = (const float4*)(A + ((size_t)j * KD + k0) * 8);
        float av[16];
        ((float4*)av)[0] = src[0];
        ((float4*)av)[1] = src[1];
        ((float4*)av)[2] = src[2];
        ((float4*)av)[3] = src[3];
        const float s0 = pb * Pc[k0];
        const float s1 = pb * Pc[k0 + 1];
        #pragma unroll
        for (int x = 0; x < 8; ++x) {
            ushort2 w;
            w.x = f2bf(av[x] * s0);
            w.y = f2bf(av[8 + x] * s1);
            *(ushort2*)(Wbf + (size_t)x * PLANE + (size_t)j * KD + k0) = w;
        }
    } else {
        // ---- B-pack: transpose [k][i] -> [i][k] through LDS ----
        const int tb = b - 512;
        const int k0 = (tb / 16) * 32;
        const int i0 = (tb % 16) * 32;
        #pragma unroll
        for (int p = 0; p < 4; ++p) {
            const int idx = t + p * 256;
            const int dk = idx >> 5;
            const int di = idx & 31;
            const float pa = Pa[i0 + di];
            const float4* src = (const float4*)(B + ((size_t)(k0 + dk) * KD + (i0 + di)) * 8);
            float bv[8];
            ((float4*)bv)[0] = src[0];
            ((float4*)bv)[1] = src[1];
            #pragma unroll
            for (int y = 0; y < 8; ++y)
                lds[(y * 32 + di) * 40 + dk] = f2bf(bv[y] * pa);
        }
        __syncthreads();
        #pragma unroll
        for (int p = 0; p < 4; ++p) {
            const int c = t + p * 256;
            const int y = c >> 7;
            const int rem = c & 127;
            const int di = rem >> 2;
            const int dk8 = (rem & 3) * 8;
            uint4 v = *(const uint4*)&lds[(y * 32 + di) * 40 + dk8];
            *(uint4*)(Xbf + (size_t)y * PLANE + (size_t)(i0 + di) * KD + (k0 + dk8)) = v;
        }
    }
}

// ---------------------------------------------------------------------------
// Fused GEMM + C-contraction.
// grid = 1024 blocks. XCD-locality swizzle: dispatch round-robins blockIdx
// over the 8 XCDs, so give each XCD a CONTIGUOUS chunk of (tile,xy) space:
//   xcd = bid&7 owns tiles {2*xcd, 2*xcd+1} and all 64 xy of each.
// The 64 xy-blocks of a tile share the same 512 KB C tile; the tile pair
// shares X i-slabs. Working set/XCD ~= 4 MB = one L2.
// T_xy[i,j] = sum_k X[y][i][k] * W[x][j][k]  (both k-contiguous, "gemm_bt")
// BK=64 (m97-proven config): 8 k-iterations, 32 MFMA/wave per barrier pair.
// probs[x,y,z] += sum_{i,j in tile} T[i,j] * C[i,j,z]
// ---------------------------------------------------------------------------
__global__ __launch_bounds__(256, 3) void gemm_kernel(const float* __restrict__ yp,
                                                      const unsigned short* __restrict__ Wbf,
                                                      const unsigned short* __restrict__ Xbf,
                                                      float* __restrict__ probs_acc) {
    __shared__ unsigned short Xs[128 * 64];   // [i_local][k] 128B rows
    __shared__ unsigned short Ws[128 * 64];   // [j_local][k]
    __shared__ float red[4][8];

    const int bid = blockIdx.x;
    // bijective un-swizzle: bid&7 = xcd, bid>>3 in [0,128) = tile_lo*64 + xy
    const int tile = ((bid & 7) << 1) | ((bid >> 9) & 1);
    const int xy = (bid >> 3) & 63;
    const int x = xy >> 3, y = xy & 7;
    const int i0 = (tile >> 2) * 128;
    const int j0 = (tile & 3) * 128;

    const unsigned short* Xg = Xbf + (size_t)y * PLANE;  // [i][k]
    const unsigned short* Wg = Wbf + (size_t)x * PLANE;  // [j][k]

    const int t = threadIdx.x;
    const int w = t >> 6;            // wave 0..3
    const int l = t & 63;
    const int wm = w >> 1, wn = w & 1;
    const int lm = l & 15, quad = l >> 4;
    const int srow = l >> 3;          // staging row within 8-row chunk
    const int scol = (l & 7) * 8;     // staging k-offset (elements)

    v4f acc[4][4];
    #pragma unroll
    for (int a = 0; a < 4; ++a)
        #pragma unroll
        for (int bb = 0; bb < 4; ++bb)
            acc[a][bb] = (v4f){0.f, 0.f, 0.f, 0.f};

    for (int kt = 0; kt < 8; ++kt) {
        const int kbase = kt * 64;
        // each wave stages its own 32-row band of both tiles: 4 issues each.
        #pragma unroll
        for (int q = 0; q < 4; ++q) {
            const int row = w * 32 + q * 8 + srow;
            async16(Xg + ((size_t)(i0 + row) * KD + kbase + scol),
                    &Xs[(w * 32 + q * 8) * 64]);
            async16(Wg + ((size_t)(j0 + row) * KD + kbase + scol),
                    &Ws[(w * 32 + q * 8) * 64]);
        }
        __syncthreads();   // compiler drains vmcnt before s_barrier

        #pragma unroll
        for (int kk = 0; kk < 2; ++kk) {
            v8s aF[4], bF[4];
            #pragma unroll
            for (int mt = 0; mt < 4; ++mt)
                aF[mt] = *(const v8s*)&Xs[(wm * 64 + mt * 16 + lm) * 64 + kk * 32 + quad * 8];
            #pragma unroll
            for (int nt = 0; nt < 4; ++nt)
                bF[nt] = *(const v8s*)&Ws[(wn * 64 + nt * 16 + lm) * 64 + kk * 32 + quad * 8];
            #pragma unroll
            for (int mt = 0; mt < 4; ++mt)
                #pragma unroll
                for (int nt = 0; nt < 4; ++nt)
                    acc[mt][nt] = __builtin_amdgcn_mfma_f32_16x16x32_bf16(
                        aF[mt], bF[nt], acc[mt][nt], 0, 0, 0);
        }
        __syncthreads();
    }

    // ---- epilogue: contract T tile with C[i,j,0..7] (fp32, L2-resident) ----
    const float* Cptr = yp + 3 * KD + 2 * (size_t)SZ;
    float zacc[8];
    #pragma unroll
    for (int z = 0; z < 8; ++z) zacc[z] = 0.f;

    #pragma unroll
    for (int mt = 0; mt < 4; ++mt) {
        #pragma unroll
        for (int nt = 0; nt < 4; ++nt) {
            #pragma unroll
            for (int r = 0; r < 4; ++r) {
                const int gi = i0 + wm * 64 + mt * 16 + quad * 4 + r;  // D row = M = i
                const int gj = j0 + wn * 64 + nt * 16 + lm;            // D col = N = j
                const float4* cp = (const float4*)(Cptr + ((size_t)gi * KD + gj) * 8);
                const float4 c0 = cp[0], c1 = cp[1];
                const float tv = acc[mt][nt][r];
                zacc[0] += tv * c0.x; zacc[1] += tv * c0.y;
                zacc[2] += tv * c0.z; zacc[3] += tv * c0.w;
                zacc[4] += tv * c1.x; zacc[5] += tv * c1.y;
                zacc[6] += tv * c1.z; zacc[7] += tv * c1.w;
            }
        }
    }
    #pragma unroll
    for (int z = 0; z < 8; ++z) {
        float v = zacc[z];
        for (int off = 32; off > 0; off >>= 1)
            v += __shfl_xor(v, off, 64);
        zacc[z] = v;
    }
    if (l == 0) {
        #pragma unroll
        for (int z = 0; z < 8; ++z) red[w][z] = zacc[z];
    }
    __syncthreads();
    if (t < 8) {
        const float s = red[0][t] + red[1][t] + red[2][t] + red[3][t];
        atomicAdd(&probs_acc[xy * 8 + t], s);
    }
}

// ---------------------------------------------------------------------------
// Finalize: KL divergence + emit probs. out[0]=d, out[1..512]=probs.
// ---------------------------------------------------------------------------
__global__ __launch_bounds__(512) void finalize_kernel(const float* __restrict__ probs_acc,
                                                       const float* __restrict__ y_true,
                                                       float* __restrict__ out) {
    __shared__ float red[8];
    const int t = threadIdx.x;
    const float p = probs_acc[t];
    out[1 + t] = p;
    const float ytv = y_true[t];
    const float pc = fminf(fmaxf(p, 1e-10f), 1.0f);
    float term = ytv * (logf(ytv + 1e-10f) - logf(pc));
    for (int off = 32; off > 0; off >>= 1)
        term += __shfl_xor(term, off, 64);
    if ((t & 63) == 0) red[t >> 6] = term;
    __syncthreads();
    if (t == 0) {
        float s = 0.f;
        #pragma unroll
        for (int i = 0; i < 8; ++i) s += red[i];
        out[0] = s;
    }
}

extern "C" void kernel_launch(void* const* d_in, const int* in_sizes, int n_in,
                              void* d_out, int out_size, void* d_ws, size_t ws_size,
                              hipStream_t stream) {
    const float* yp = (const float*)d_in[0];
    const float* yt = (const float*)d_in[1];
    float* out = (float*)d_out;

    unsigned short* Wbf = (unsigned short*)d_ws;              // 8 planes of A-weighted: 4 MB
    unsigned short* Xbf = Wbf + (size_t)8 * PLANE;            // 8 planes of B-weighted: 4 MB
    float* probs_acc = (float*)(Xbf + (size_t)8 * PLANE);     // 512 floats

    pack_kernel<<<768, 256, 0, stream>>>(yp, Wbf, Xbf, probs_acc);
    gemm_kernel<<<1024, 256, 0, stream>>>(yp, Wbf, Xbf, probs_acc);
    finalize_kernel<<<1, 512, 0, stream>>>(probs_acc, yt, out);
}

// Round 2
// 101.624 us; speedup vs baseline: 1.4303x; 1.2381x over previous
//
#include <hip/hip_runtime.h>
#include <hip/hip_bf16.h>
#include <stdint.h>

#define KD 512
#define OD 8
#define SZ (KD*KD*OD)       // 2097152 elements per tensor (A,B,C)
#define PLANE (KD*KD)       // 262144

typedef short v8s __attribute__((ext_vector_type(8)));
typedef float v4f __attribute__((ext_vector_type(4)));

#define GLOBAL_AS __attribute__((address_space(1)))
#define LDS_AS __attribute__((address_space(3)))

static __device__ __forceinline__ unsigned short f2bf(float f) {
    union { float f; unsigned int u; } v; v.f = f;
    unsigned int u = v.u;
    unsigned int r = u + 0x7FFF + ((u >> 16) & 1);   // RNE
    return (unsigned short)(r >> 16);
}

static __device__ __forceinline__ void async16(const unsigned short* g, unsigned short* l) {
    __builtin_amdgcn_global_load_lds((const GLOBAL_AS void*)g, (LDS_AS void*)l, 16, 0, 0);
}

// swizzled fragment read: LDS rows are 128 B; element col C stored at byte
// C*2 ^ ((row&7)<<4).  row&7 == lm&7 for all fragment rows.
static __device__ __forceinline__ v8s lds_frag(const unsigned short* base, int row, int colb) {
    return *(const v8s*)((const char*)base + row * 128 + (colb ^ ((row & 7) << 4)));
}

// ---------------------------------------------------------------------------
// Pack: W[x][j][k] = A[j,k,x]*Pb[j]*Pc[k]   (bf16, k-contiguous)
//       X[y][i][k] = B[k,i,y]*Pa[i]         (bf16, k-contiguous, via LDS transpose)
// blocks [0,256): A-pack, 2 j-rows each. blocks [256,512): B-pack 32x32 tiles
// with XOR-swizzled LDS (64 B rows, byte ^= (di&7)<<4) to cut the 8-way
// ds_write_b16 bank conflict of the old padded layout to 4-way.
// block 0 also zeroes the probs accumulator (ws is poisoned each call).
// ---------------------------------------------------------------------------
__global__ __launch_bounds__(256) void pack_kernel(const float* __restrict__ yp,
                                                   unsigned short* __restrict__ Wbf,
                                                   unsigned short* __restrict__ Xbf,
                                                   float* __restrict__ probs_acc) {
    __shared__ unsigned short lds[8 * 32 * 32];   // [y][di][dk] 64B rows, swizzled
    const float* Pa = yp;
    const float* Pb = yp + KD;
    const float* Pc = yp + 2 * KD;
    const float* A  = yp + 3 * KD;
    const float* B  = A + SZ;
    const int b = blockIdx.x;
    const int t = threadIdx.x;

    if (b == 0) { probs_acc[t] = 0.0f; probs_acc[t + 256] = 0.0f; }

    if (b < 256) {
        // ---- A-pack: j = 2b, 2b+1; each thread handles k0 = 2t, 2t+1 ----
        #pragma unroll
        for (int jj = 0; jj < 2; ++jj) {
            const int j = b * 2 + jj;
            const float pb = Pb[j];
            const int k0 = 2 * t;
            const float4* src = (const float4*)(A + ((size_t)j * KD + k0) * 8);
            float av[16];
            ((float4*)av)[0] = src[0];
            ((float4*)av)[1] = src[1];
            ((float4*)av)[2] = src[2];
            ((float4*)av)[3] = src[3];
            const float s0 = pb * Pc[k0];
            const float s1 = pb * Pc[k0 + 1];
            #pragma unroll
            for (int x = 0; x < 8; ++x) {
                ushort2 w;
                w.x = f2bf(av[x] * s0);
                w.y = f2bf(av[8 + x] * s1);
                *(ushort2*)(Wbf + (size_t)x * PLANE + (size_t)j * KD + k0) = w;
            }
        }
    } else {
        // ---- B-pack: transpose [k][i] -> [i][k] through swizzled LDS ----
        const int tb = b - 256;
        const int k0 = (tb / 16) * 32;
        const int i0 = (tb % 16) * 32;
        char* ldsb = (char*)lds;
        #pragma unroll
        for (int p = 0; p < 4; ++p) {
            const int idx = t + p * 256;
            const int dk = idx >> 5;
            const int di = idx & 31;
            const float pa = Pa[i0 + di];
            const float4* src = (const float4*)(B + ((size_t)(k0 + dk) * KD + (i0 + di)) * 8);
            float bv[8];
            ((float4*)bv)[0] = src[0];
            ((float4*)bv)[1] = src[1];
            const int swz = (di & 7) << 4;
            #pragma unroll
            for (int y = 0; y < 8; ++y)
                *(unsigned short*)(ldsb + (y * 32 + di) * 64 + ((dk * 2) ^ swz)) =
                    f2bf(bv[y] * pa);
        }
        __syncthreads();
        #pragma unroll
        for (int p = 0; p < 4; ++p) {
            const int c = t + p * 256;
            const int y = c >> 7;
            const int rem = c & 127;
            const int di = rem >> 2;
            const int dk8 = (rem & 3) * 8;
            uint4 v = *(const uint4*)(ldsb + (y * 32 + di) * 64 + ((dk8 * 2) ^ ((di & 7) << 4)));
            *(uint4*)(Xbf + (size_t)y * PLANE + (size_t)(i0 + di) * KD + (k0 + dk8)) = v;
        }
    }
}

// ---------------------------------------------------------------------------
// Fused GEMM + C-contraction.
// grid = 1024.  Each block: one 64x64 (i,j) tile x FOUR (x,y) pairs (2x2),
// so the C tile (64*64*8 fp32 = 128 KB) is read once per 4 xy -> C traffic
// 128 MB total (was 512 MB).  Same MFMA count (32/wave per k-step), same
// staging bytes (4 tiles of 64x64 bf16 = 32 KB per k-step).
// XCD swizzle: xcd = bid&7 owns a 2x4 band of ij-tiles x all 16 xy-groups;
// working set ~4 MB = one L2.  1024 % 8 == 0 -> bijective.
// LDS is XOR-swizzled (T2, both-sides rule 21): global source column is
// pre-swizzled so the linear global_load_lds dest yields
// LDS[row][colb ^ ((row&7)<<4)]; reads apply the same XOR.
// ---------------------------------------------------------------------------
__global__ __launch_bounds__(256, 3) void gemm_kernel(const float* __restrict__ yp,
                                                      const unsigned short* __restrict__ Wbf,
                                                      const unsigned short* __restrict__ Xbf,
                                                      float* __restrict__ probs_acc) {
    __shared__ unsigned short S[4][64 * 64];  // 0,1: X[y0+dy]; 2,3: W[x0+dx]
    __shared__ float red[4][32];

    const int bid = blockIdx.x;
    const int xcd = bid & 7;
    const int local = bid >> 3;          // 0..127
    const int tl = local >> 4;           // 0..7  tile-local
    const int group = local & 15;        // 0..15 xy-group
    const int i_t = ((xcd >> 1) << 1) | (tl >> 2);   // 0..7
    const int j_t = ((xcd & 1) << 2) | (tl & 3);     // 0..7
    const int i0 = i_t * 64, j0 = j_t * 64;
    const int x0 = (group >> 2) * 2, y0 = (group & 3) * 2;

    const int t = threadIdx.x;
    const int w = t >> 6;            // wave 0..3
    const int l = t & 63;
    const int wm = w >> 1, wn = w & 1;
    const int lm = l & 15, quad = l >> 4;
    const int srow = l >> 3;                     // staging row within 8-row issue
    const int scol = ((l & 7) ^ srow) * 8;       // pre-swizzled source col (elems)

    // wave w stages tile w for every k-step
    const unsigned short* gsrc;
    if (w < 2) gsrc = Xbf + (size_t)(y0 + w) * PLANE + (size_t)i0 * KD;
    else       gsrc = Wbf + (size_t)(x0 + (w - 2)) * PLANE + (size_t)j0 * KD;
    const unsigned short* gthr = gsrc + (size_t)srow * KD + scol;

    v4f acc[2][2][2][2];   // [dy][dx][mt][nt]
    #pragma unroll
    for (int a = 0; a < 2; ++a)
      #pragma unroll
      for (int bb = 0; bb < 2; ++bb)
        #pragma unroll
        for (int c = 0; c < 2; ++c)
          #pragma unroll
          for (int d = 0; d < 2; ++d)
            acc[a][bb][c][d] = (v4f){0.f, 0.f, 0.f, 0.f};

    for (int kt = 0; kt < 8; ++kt) {
        const int kbase = kt * 64;
        #pragma unroll
        for (int q = 0; q < 8; ++q)
            async16(gthr + (size_t)(q * 8) * KD + kbase, &S[w][q * 512]);
        __syncthreads();   // drains vmcnt before s_barrier

        #pragma unroll
        for (int kk = 0; kk < 2; ++kk) {
            const int colb = kk * 64 + quad * 16;   // byte col of 16B fragment
            v8s aF[2][2], bF[2][2];
            #pragma unroll
            for (int dy = 0; dy < 2; ++dy)
                #pragma unroll
                for (int mt = 0; mt < 2; ++mt)
                    aF[dy][mt] = lds_frag(&S[dy][0], wm * 32 + mt * 16 + lm, colb);
            #pragma unroll
            for (int dx = 0; dx < 2; ++dx)
                #pragma unroll
                for (int nt = 0; nt < 2; ++nt)
                    bF[dx][nt] = lds_frag(&S[2 + dx][0], wn * 32 + nt * 16 + lm, colb);
            #pragma unroll
            for (int dy = 0; dy < 2; ++dy)
                #pragma unroll
                for (int dx = 0; dx < 2; ++dx)
                    #pragma unroll
                    for (int mt = 0; mt < 2; ++mt)
                        #pragma unroll
                        for (int nt = 0; nt < 2; ++nt)
                            acc[dy][dx][mt][nt] = __builtin_amdgcn_mfma_f32_16x16x32_bf16(
                                aF[dy][mt], bF[dx][nt], acc[dy][dx][mt][nt], 0, 0, 0);
        }
        __syncthreads();
    }

    // ---- epilogue: contract 4 T tiles with shared C[i,j,0..7] (fp32, L2) ----
    const float* Cp = yp + 3 * KD + 2 * (size_t)SZ;
    float zacc[2][2][8];
    #pragma unroll
    for (int dy = 0; dy < 2; ++dy)
      #pragma unroll
      for (int dx = 0; dx < 2; ++dx)
        #pragma unroll
        for (int z = 0; z < 8; ++z) zacc[dy][dx][z] = 0.f;

    #pragma unroll
    for (int mt = 0; mt < 2; ++mt) {
        #pragma unroll
        for (int nt = 0; nt < 2; ++nt) {
            #pragma unroll
            for (int r = 0; r < 4; ++r) {
                const int gi = i0 + wm * 32 + mt * 16 + quad * 4 + r;  // D row = i
                const int gj = j0 + wn * 32 + nt * 16 + lm;            // D col = j
                const float4* cp = (const float4*)(Cp + ((size_t)gi * KD + gj) * 8);
                const float4 c0 = cp[0], c1 = cp[1];
                #pragma unroll
                for (int dy = 0; dy < 2; ++dy) {
                    #pragma unroll
                    for (int dx = 0; dx < 2; ++dx) {
                        const float tv = acc[dy][dx][mt][nt][r];
                        zacc[dy][dx][0] += tv * c0.x; zacc[dy][dx][1] += tv * c0.y;
                        zacc[dy][dx][2] += tv * c0.z; zacc[dy][dx][3] += tv * c0.w;
                        zacc[dy][dx][4] += tv * c1.x; zacc[dy][dx][5] += tv * c1.y;
                        zacc[dy][dx][6] += tv * c1.z; zacc[dy][dx][7] += tv * c1.w;
                    }
                }
            }
        }
    }
    #pragma unroll
    for (int dy = 0; dy < 2; ++dy)
      #pragma unroll
      for (int dx = 0; dx < 2; ++dx)
        #pragma unroll
        for (int z = 0; z < 8; ++z) {
            float v = zacc[dy][dx][z];
            for (int off = 32; off > 0; off >>= 1)
                v += __shfl_xor(v, off, 64);
            zacc[dy][dx][z] = v;
        }
    if (l == 0) {
        #pragma unroll
        for (int dy = 0; dy < 2; ++dy)
          #pragma unroll
          for (int dx = 0; dx < 2; ++dx)
            #pragma unroll
            for (int z = 0; z < 8; ++z)
                red[w][(dy * 2 + dx) * 8 + z] = zacc[dy][dx][z];
    }
    __syncthreads();
    if (t < 32) {
        const float s = red[0][t] + red[1][t] + red[2][t] + red[3][t];
        const int p = t >> 3;              // dy*2+dx
        const int dy = p >> 1, dx = p & 1, z = t & 7;
        atomicAdd(&probs_acc[((x0 + dx) * 8 + (y0 + dy)) * 8 + z], s);
    }
}

// ---------------------------------------------------------------------------
// Finalize: KL divergence + emit probs. out[0]=d, out[1..512]=probs.
// ---------------------------------------------------------------------------
__global__ __launch_bounds__(512) void finalize_kernel(const float* __restrict__ probs_acc,
                                                       const float* __restrict__ y_true,
                                                       float* __restrict__ out) {
    __shared__ float red[8];
    const int t = threadIdx.x;
    const float p = probs_acc[t];
    out[1 + t] = p;
    const float ytv = y_true[t];
    const float pc = fminf(fmaxf(p, 1e-10f), 1.0f);
    float term = ytv * (logf(ytv + 1e-10f) - logf(pc));
    for (int off = 32; off > 0; off >>= 1)
        term += __shfl_xor(term, off, 64);
    if ((t & 63) == 0) red[t >> 6] = term;
    __syncthreads();
    if (t == 0) {
        float s = 0.f;
        #pragma unroll
        for (int i = 0; i < 8; ++i) s += red[i];
        out[0] = s;
    }
}

extern "C" void kernel_launch(void* const* d_in, const int* in_sizes, int n_in,
                              void* d_out, int out_size, void* d_ws, size_t ws_size,
                              hipStream_t stream) {
    const float* yp = (const float*)d_in[0];
    const float* yt = (const float*)d_in[1];
    float* out = (float*)d_out;

    unsigned short* Wbf = (unsigned short*)d_ws;              // 8 planes of A-weighted: 4 MB
    unsigned short* Xbf = Wbf + (size_t)8 * PLANE;            // 8 planes of B-weighted: 4 MB
    float* probs_acc = (float*)(Xbf + (size_t)8 * PLANE);     // 512 floats

    pack_kernel<<<512, 256, 0, stream>>>(yp, Wbf, Xbf, probs_acc);
    gemm_kernel<<<1024, 256, 0, stream>>>(yp, Wbf, Xbf, probs_acc);
    finalize_kernel<<<1, 512, 0, stream>>>(probs_acc, yt, out);
}